// Round 3
// baseline (510.024 us; speedup 1.0000x reference)
//
#include <hip/hip_runtime.h>
#include <hip/hip_cooperative_groups.h>
#include <stdint.h>

namespace cg = cooperative_groups;

#define N_NODES 8192
#define NE      131072
#define DCH     128      // feature channels
#define WPR     256      // 32-bit words per bitmap row (8192/32)
#define MAXDEG  128      // neighbor-list capacity per node (Poisson(32); P(>128) ~ 0)
#define EPS     1e-5f

// Single cooperative kernel, 5 phases separated by grid.sync().
// Phases are block/wave-stride loops -> correct for any grid size.
__global__ __launch_bounds__(256) void gcn_fused(
    const float* __restrict__ x,      // [8192][128]
    const void*  __restrict__ ei_raw, // [2][131072] int64 (or int32 if narrowed)
    const float* __restrict__ W,      // [128][128]
    const float* __restrict__ bias,   // [128]
    float* __restrict__ out,          // [8192][128]
    uint32_t* __restrict__ bm,        // ws: 8 MB adjacency bitmap
    float* __restrict__ dinv,         // ws: 32 KB
    int* __restrict__ cnts,           // ws: 32 KB
    uint16_t* __restrict__ nbr,       // ws: 2 MB compact neighbor lists
    float* __restrict__ agg)          // ws: 4 MB aggregated features
{
    cg::grid_group grid = cg::this_grid();
    const int tid      = threadIdx.x;
    const int lane     = tid & 63;
    const int gtid     = blockIdx.x * 256 + tid;
    const int nthreads = gridDim.x * 256;
    const int waveId   = blockIdx.x * 4 + (tid >> 6);
    const int nWaves   = gridDim.x * 4;

    // ---------------- P0: zero the bitmap (8 MB) ----------------
    {
        uint4* bm16 = (uint4*)bm;
        const uint4 z = {0u, 0u, 0u, 0u};
        for (int i = gtid; i < N_NODES * (WPR / 4); i += nthreads) bm16[i] = z;
    }
    grid.sync();

    // ---------------- P1: edges -> symmetric bitmap ----------------
    // Layout detect: if int64, all first-64 values < N; if int32, the packed
    // high halves make that impossible. Wave-uniform, ~free (L1 broadcast).
    {
        const long long* p64 = (const long long*)ei_raw;
        const int*       p32 = (const int*)ei_raw;
        bool is64 = __all((unsigned long long)p64[lane] < (unsigned long long)N_NODES);
        for (int e = gtid; e < NE; e += nthreads) {
            int r, c;
            if (is64) { r = (int)p64[e]; c = (int)p64[NE + e]; }
            else      { r = p32[e];      c = p32[NE + e]; }
            atomicOr(&bm[r * WPR + (c >> 5)], 1u << (c & 31));   // bit-set is idempotent:
            atomicOr(&bm[c * WPR + (r >> 5)], 1u << (r & 31));   // dedup + symmetrize free
        }
    }
    grid.sync();

    // ---------------- P2: degree -> dinv, extract neighbor lists ----------------
    // One wave per node: lane holds 128 bits (uint4). Shuffle prefix-scan gives
    // each lane its write offset; bits emitted once to a compact global list.
    {
        const uint4* bm4 = (const uint4*)bm;
        for (int n = waveId; n < N_NODES; n += nWaves) {
            uint4 w = bm4[(size_t)n * 64 + lane];
            int c = __popc(w.x) + __popc(w.y) + __popc(w.z) + __popc(w.w);
            int pre = c;
            #pragma unroll
            for (int d = 1; d < 64; d <<= 1) {
                int v = __shfl_up(pre, d);
                if (lane >= d) pre += v;
            }
            int tot  = __shfl(pre, 63);      // inclusive scan at lane 63 = row degree
            int excl = pre - c;
            if (lane == 0) {
                dinv[n] = 1.0f / sqrtf((float)tot + 1.0f + EPS);  // rowsum(A_sym + I) = tot + 1
                cnts[n] = tot > MAXDEG ? MAXDEG : tot;
            }
            uint32_t wd[4] = {w.x, w.y, w.z, w.w};
            int basebit = lane * 128;
            int o = excl;
            #pragma unroll
            for (int m = 0; m < 4; ++m) {
                uint32_t v = wd[m];
                while (v) {
                    int b = __ffs(v) - 1; v &= v - 1;
                    if (o < MAXDEG) nbr[(size_t)n * MAXDEG + o] = (uint16_t)(basebit + m * 32 + b);
                    ++o;
                }
            }
        }
    }
    grid.sync();

    // ---------------- P3: aggregate  agg[n] = dinv[n]*(sum_j dinv[j] x[j] + dinv[n] x[n]) ----
    // One wave per node, lane = 2 channels (float2, 512B/row coalesced).
    // Neighbor index broadcast: shuffle + readfirstlane -> scalar base address.
    {
        const float2* x2   = (const float2*)x;
        float2*       agg2 = (float2*)agg;
        for (int n = waveId; n < N_NODES; n += nWaves) {
            int   cnt = __builtin_amdgcn_readfirstlane(cnts[n]);
            float di  = dinv[n];
            float2 own = x2[(size_t)n * 64 + lane];
            float2 a0, a1, a2, a3;
            a0.x = di * own.x; a0.y = di * own.y;           // +I contribution
            a1.x = a1.y = a2.x = a2.y = a3.x = a3.y = 0.0f;
            int jl = (int)nbr[(size_t)n * MAXDEG + lane];        // entries >= cnt are garbage,
            int jh = (int)nbr[(size_t)n * MAXDEG + 64 + lane];   // never dereferenced (clamped)
            for (int k = 0; k < cnt; k += 4) {
                #define NBR_J(kk) __builtin_amdgcn_readfirstlane((kk) < 64 ? __shfl(jl, (kk)) : __shfl(jh, (kk) - 64))
                int k0 = k, k1 = k + 1, k2 = k + 2, k3 = k + 3;
                int j0 = NBR_J(k0); int j1 = NBR_J(k1); int j2 = NBR_J(k2); int j3 = NBR_J(k3);
                bool v1 = k1 < cnt, v2 = k2 < cnt, v3 = k3 < cnt;
                j1 = v1 ? j1 : n; j2 = v2 ? j2 : n; j3 = v3 ? j3 : n;   // clamp BEFORE address use
                float w0 = dinv[j0];
                float w1 = v1 ? dinv[j1] : 0.0f;
                float w2 = v2 ? dinv[j2] : 0.0f;
                float w3 = v3 ? dinv[j3] : 0.0f;
                float2 q0 = x2[(size_t)j0 * 64 + lane];
                float2 q1 = x2[(size_t)j1 * 64 + lane];
                float2 q2 = x2[(size_t)j2 * 64 + lane];
                float2 q3 = x2[(size_t)j3 * 64 + lane];
                a0.x += w0 * q0.x; a0.y += w0 * q0.y;
                a1.x += w1 * q1.x; a1.y += w1 * q1.y;
                a2.x += w2 * q2.x; a2.y += w2 * q2.y;
                a3.x += w3 * q3.x; a3.y += w3 * q3.y;
                #undef NBR_J
            }
            float2 r;
            r.x = di * (a0.x + a1.x + a2.x + a3.x);
            r.y = di * (a0.y + a1.y + a2.y + a3.y);
            agg2[(size_t)n * 64 + lane] = r;
        }
    }
    grid.sync();

    // ---------------- P4: out = agg @ W + bias ----------------
    // Block = 4 rows x 128 cols. A-rows staged in 2 KB LDS (broadcast reads);
    // W row segments 512 B/wave coalesced, 64 KB total -> L1/L2 hot.
    {
        __shared__ float sA[4][DCH];
        const float2* W2   = (const float2*)W;
        const float2* b2   = (const float2*)bias;
        const float2* agg2 = (const float2*)agg;
        float2*       out2 = (float2*)out;
        for (int g = blockIdx.x; g < N_NODES / 4; g += gridDim.x) {
            __syncthreads();            // protect sA reuse across g-iterations
            {
                int row = tid >> 6, cp = tid & 63;
                float2 v = agg2[(size_t)(g * 4 + row) * 64 + cp];
                sA[row][cp * 2] = v.x; sA[row][cp * 2 + 1] = v.y;
            }
            __syncthreads();
            int cp = tid & 63, rp = tid >> 6;
            float2 acc; acc.x = acc.y = 0.0f;
            #pragma unroll 8
            for (int k = 0; k < DCH; ++k) {
                float  a  = sA[rp][k];                 // LDS broadcast (wave-uniform addr)
                float2 wv = W2[k * 64 + cp];           // 512 B/wave coalesced
                acc.x += a * wv.x; acc.y += a * wv.y;
            }
            float2 bb = b2[cp];
            acc.x += bb.x; acc.y += bb.y;
            out2[(size_t)(g * 4 + rp) * 64 + cp] = acc;
        }
    }
}

// ---------------------------------------------------------------------------
extern "C" void kernel_launch(void* const* d_in, const int* in_sizes, int n_in,
                              void* d_out, int out_size, void* d_ws, size_t ws_size,
                              hipStream_t stream) {
    const float* xp  = (const float*)d_in[0];
    const void*  eip = d_in[1];
    const float* Wp  = (const float*)d_in[2];
    const float* bp  = (const float*)d_in[3];
    float*       op  = (float*)d_out;

    uint8_t* ws = (uint8_t*)d_ws;
    uint32_t* bmp   = (uint32_t*)ws;                                        // 8 MB
    float*    dinvp = (float*)   (ws + (size_t)8 * 1024 * 1024);            // 32 KB
    int*      cntp  = (int*)     (ws + (size_t)8 * 1024 * 1024 + 32 * 1024);// 32 KB
    uint16_t* nbrp  = (uint16_t*)(ws + (size_t)8 * 1024 * 1024 + 64 * 1024);// 2 MB
    float*    aggp  = (float*)   (ws + (size_t)8 * 1024 * 1024 + 64 * 1024
                                     + (size_t)2 * 1024 * 1024);            // 4 MB

    // Size grid to guaranteed co-residency (cooperative requirement).
    int dev = 0; hipGetDevice(&dev);
    int numCU = 0; hipDeviceGetAttribute(&numCU, hipDeviceAttributeMultiprocessorCount, dev);
    int maxBlk = 0;
    hipOccupancyMaxActiveBlocksPerMultiprocessor(&maxBlk, gcn_fused, 256, 0);
    long long g = (long long)numCU * (long long)maxBlk;
    if (g > 2048) g = 2048;
    if (g < 1) g = 1;

    void* args[] = {(void*)&xp, (void*)&eip, (void*)&Wp, (void*)&bp, (void*)&op,
                    (void*)&bmp, (void*)&dinvp, (void*)&cntp, (void*)&nbrp, (void*)&aggp};
    hipLaunchCooperativeKernel((const void*)gcn_fused, dim3((int)g), dim3(256),
                               args, 0, stream);
}

// Round 4
// 105.372 us; speedup vs baseline: 4.8402x; 4.8402x over previous
//
#include <hip/hip_runtime.h>
#include <stdint.h>

#define N_NODES 8192
#define NE      131072
#define DCH     128
#define WPR     256          // 32-bit words per bitmap row
#define MAXDEG  128          // list capacity (deg ~ Poisson(32), max ~60)
#define ZROW    8192         // dummy node index -> zero row of y
#define EPS     1e-5f

// ---------------------------------------------------------------------------
// Edges -> symmetric adjacency bitmap. Bit-set idempotent => dedup (matches
// .at[].set(1.0)) + symmetrize (both directions) free. Inline int64/int32
// layout detect per wave: if data is int32-packed, the high halves of the
// first 64 qwords are node ids (>=2^32 as qwords) -> __all fails.
__global__ __launch_bounds__(256) void edge_kernel(const void* __restrict__ ei_raw,
                                                   uint32_t* __restrict__ bm) {
    int lane = threadIdx.x & 63;
    const long long* p64 = (const long long*)ei_raw;
    const int*       p32 = (const int*)ei_raw;
    bool is64 = __all((unsigned long long)p64[lane] < (unsigned long long)N_NODES);
    int e = blockIdx.x * 256 + threadIdx.x;
    int r, c;
    if (is64) { r = (int)p64[e]; c = (int)p64[NE + e]; }
    else      { r = p32[e];      c = p32[NE + e]; }
    atomicOr(&bm[r * WPR + (c >> 5)], 1u << (c & 31));
    atomicOr(&bm[c * WPR + (r >> 5)], 1u << (r & 31));
}

// ---------------------------------------------------------------------------
// One wave per node: popcount row -> dinv, emit compact u16 neighbor list
// (shuffle prefix-scan for offsets), pad list to multiple of 8 with ZROW.
// Also zeroes y[ZROW] (block 0) so padded entries add 0 in aggregation.
__global__ __launch_bounds__(256) void extract_kernel(const uint4* __restrict__ bm4,
                                                      float* __restrict__ dinv,
                                                      int* __restrict__ cnts,
                                                      uint16_t* __restrict__ nbr,
                                                      float* __restrict__ y) {
    if (blockIdx.x == 0 && threadIdx.x < DCH)
        y[(size_t)ZROW * DCH + threadIdx.x] = 0.0f;

    int lane = threadIdx.x & 63;
    int node = blockIdx.x * 4 + (threadIdx.x >> 6);
    uint4 w = bm4[(size_t)node * 64 + lane];
    int c = __popc(w.x) + __popc(w.y) + __popc(w.z) + __popc(w.w);
    int pre = c;
    #pragma unroll
    for (int d = 1; d < 64; d <<= 1) {
        int v = __shfl_up(pre, d);
        if (lane >= d) pre += v;
    }
    int tot  = __shfl(pre, 63);          // row degree (incl self-bit if present)
    int excl = pre - c;
    int cnt  = tot > MAXDEG ? MAXDEG : tot;
    int kpad = (cnt + 7) & ~7;
    if (lane == 0) {
        dinv[node] = 1.0f / sqrtf((float)tot + 1.0f + EPS);  // rowsum(A_sym)+diag(+I)
        cnts[node] = kpad;
    }
    uint32_t wd[4] = {w.x, w.y, w.z, w.w};
    int basebit = lane * 128;
    int o = excl;
    #pragma unroll
    for (int m = 0; m < 4; ++m) {
        uint32_t v = wd[m];
        while (v) {
            int b = __ffs(v) - 1; v &= v - 1;
            if (o < MAXDEG) nbr[(size_t)node * MAXDEG + o] = (uint16_t)(basebit + m * 32 + b);
            ++o;
        }
    }
    int p = cnt + lane;                  // at most 7 lanes pad
    if (p < kpad) nbr[(size_t)node * MAXDEG + p] = (uint16_t)ZROW;
}

// ---------------------------------------------------------------------------
// y = dinv ⊙ (x @ W).  64x64 tile, 256 threads, 4x4 per thread, f32 VALU
// (no fp32 MFMA on CDNA4). x tile staged in padded LDS; W hot in L1/L2.
__global__ __launch_bounds__(256) void gemm_kernel(const float* __restrict__ X,
                                                   const float* __restrict__ W,
                                                   const float* __restrict__ dinv,
                                                   float* __restrict__ y) {
    __shared__ float sA[64][132];
    int t = threadIdx.x;
    int row0 = blockIdx.x * 64;
    int col0 = blockIdx.y * 64;
    {
        int k4 = t & 31;
        int r  = t >> 5;
        #pragma unroll
        for (int p = 0; p < 8; ++p) {
            float4 v = *(const float4*)&X[(size_t)(row0 + r + p * 8) * DCH + k4 * 4];
            *(float4*)&sA[r + p * 8][k4 * 4] = v;
        }
    }
    __syncthreads();

    int tx = t & 15, ty = t >> 4;
    int cg = col0 + tx * 4;
    int r0 = ty * 4;
    float acc[4][4] = {};
    #pragma unroll 4
    for (int k = 0; k < DCH; ++k) {
        float4 w = *(const float4*)&W[(size_t)k * DCH + cg];
        float a0 = sA[r0 + 0][k];
        float a1 = sA[r0 + 1][k];
        float a2 = sA[r0 + 2][k];
        float a3 = sA[r0 + 3][k];
        acc[0][0] += a0 * w.x; acc[0][1] += a0 * w.y; acc[0][2] += a0 * w.z; acc[0][3] += a0 * w.w;
        acc[1][0] += a1 * w.x; acc[1][1] += a1 * w.y; acc[1][2] += a1 * w.z; acc[1][3] += a1 * w.w;
        acc[2][0] += a2 * w.x; acc[2][1] += a2 * w.y; acc[2][2] += a2 * w.z; acc[2][3] += a2 * w.w;
        acc[3][0] += a3 * w.x; acc[3][1] += a3 * w.y; acc[3][2] += a3 * w.z; acc[3][3] += a3 * w.w;
    }
    #pragma unroll
    for (int i = 0; i < 4; ++i) {
        float d = dinv[row0 + r0 + i];
        float4 o;
        o.x = d * acc[i][0]; o.y = d * acc[i][1]; o.z = d * acc[i][2]; o.w = d * acc[i][3];
        *(float4*)&y[(size_t)(row0 + r0 + i) * DCH + cg] = o;
    }
}

// ---------------------------------------------------------------------------
// out[n] = dinv[n] * ( sum_{k<kpad} y[nbr[n][k]] + y[n] ) + bias
// One wave per node (lane = 2 channels, 512B coalesced row loads).
// List staged to wave-private LDS; unroll-8 independent accumulators keep
// 8 row loads in flight. Padded entries hit the zero ZROW row -> add 0.
__global__ __launch_bounds__(256) void aggregate_kernel(const uint16_t* __restrict__ nbr,
                                                        const float* __restrict__ dinv,
                                                        const int* __restrict__ cnts,
                                                        const float* __restrict__ y,
                                                        const float* __restrict__ bias,
                                                        float* __restrict__ out) {
    __shared__ uint32_t s_list[4][64];   // 4 waves x 128 u16
    int w    = threadIdx.x >> 6;
    int lane = threadIdx.x & 63;
    int node = blockIdx.x * 4 + w;

    // wave-private staging: no barrier needed (same-wave LDS ops are ordered)
    s_list[w][lane] = ((const uint32_t*)nbr)[(size_t)node * (MAXDEG / 2) + lane];
    const uint16_t* sl = (const uint16_t*)s_list[w];

    int   kpad = __builtin_amdgcn_readfirstlane(cnts[node]);
    float di   = dinv[node];
    const float2* y2 = (const float2*)y;

    float2 a0 = y2[(size_t)node * 64 + lane];   // +I self term
    float2 a1 = {0, 0}, a2 = {0, 0}, a3 = {0, 0};
    float2 a4 = {0, 0}, a5 = {0, 0}, a6 = {0, 0}, a7 = {0, 0};

    for (int k = 0; k < kpad; k += 8) {
        int j0 = __builtin_amdgcn_readfirstlane((int)sl[k + 0]);
        int j1 = __builtin_amdgcn_readfirstlane((int)sl[k + 1]);
        int j2 = __builtin_amdgcn_readfirstlane((int)sl[k + 2]);
        int j3 = __builtin_amdgcn_readfirstlane((int)sl[k + 3]);
        int j4 = __builtin_amdgcn_readfirstlane((int)sl[k + 4]);
        int j5 = __builtin_amdgcn_readfirstlane((int)sl[k + 5]);
        int j6 = __builtin_amdgcn_readfirstlane((int)sl[k + 6]);
        int j7 = __builtin_amdgcn_readfirstlane((int)sl[k + 7]);
        float2 q0 = y2[(size_t)j0 * 64 + lane];
        float2 q1 = y2[(size_t)j1 * 64 + lane];
        float2 q2 = y2[(size_t)j2 * 64 + lane];
        float2 q3 = y2[(size_t)j3 * 64 + lane];
        float2 q4 = y2[(size_t)j4 * 64 + lane];
        float2 q5 = y2[(size_t)j5 * 64 + lane];
        float2 q6 = y2[(size_t)j6 * 64 + lane];
        float2 q7 = y2[(size_t)j7 * 64 + lane];
        a0.x += q0.x; a0.y += q0.y;  a1.x += q1.x; a1.y += q1.y;
        a2.x += q2.x; a2.y += q2.y;  a3.x += q3.x; a3.y += q3.y;
        a4.x += q4.x; a4.y += q4.y;  a5.x += q5.x; a5.y += q5.y;
        a6.x += q6.x; a6.y += q6.y;  a7.x += q7.x; a7.y += q7.y;
    }

    float2 bb = ((const float2*)bias)[lane];
    float2 r;
    r.x = di * (((a0.x + a1.x) + (a2.x + a3.x)) + ((a4.x + a5.x) + (a6.x + a7.x))) + bb.x;
    r.y = di * (((a0.y + a1.y) + (a2.y + a3.y)) + ((a4.y + a5.y) + (a6.y + a7.y))) + bb.y;
    ((float2*)out)[(size_t)node * 64 + lane] = r;
}

// ---------------------------------------------------------------------------
extern "C" void kernel_launch(void* const* d_in, const int* in_sizes, int n_in,
                              void* d_out, int out_size, void* d_ws, size_t ws_size,
                              hipStream_t stream) {
    const float* xp  = (const float*)d_in[0];
    const void*  eip = d_in[1];
    const float* Wp  = (const float*)d_in[2];
    const float* bp  = (const float*)d_in[3];
    float*       op  = (float*)d_out;

    uint8_t* ws = (uint8_t*)d_ws;
    uint32_t* bmp   = (uint32_t*)ws;                                          // 8 MB
    float*    dinvp = (float*)   (ws + (size_t)8 * 1024 * 1024);              // 32 KB
    int*      cntp  = (int*)     (ws + (size_t)8 * 1024 * 1024 + 32 * 1024);  // 32 KB
    uint16_t* nbrp  = (uint16_t*)(ws + (size_t)8 * 1024 * 1024 + 64 * 1024);  // 2 MB
    float*    yp    = (float*)   (ws + (size_t)10 * 1024 * 1024 + 64 * 1024); // 4.2 MB (8193 rows)

    hipMemsetAsync(bmp, 0, (size_t)N_NODES * WPR * sizeof(uint32_t), stream);
    edge_kernel<<<NE / 256, 256, 0, stream>>>(eip, bmp);
    extract_kernel<<<N_NODES / 4, 256, 0, stream>>>((const uint4*)bmp, dinvp, cntp, nbrp, yp);
    gemm_kernel<<<dim3(N_NODES / 64, 2), 256, 0, stream>>>(xp, Wp, dinvp, yp);
    aggregate_kernel<<<N_NODES / 4, 256, 0, stream>>>(nbrp, dinvp, cntp, yp, bp, op);
}